// Round 1
// baseline (222.290 us; speedup 1.0000x reference)
//
#include <hip/hip_runtime.h>

// Problem constants (from reference): V=50000, D=512, B=8192, C=32, SIGMA=1
#define DIM     512
#define BATCH   8192
#define CTX     32
#define NTHREAD 256   // each thread owns 2 consecutive elements of D (float2)

// One block per batch row b.
//  - stage the 32 context indices in LDS, readfirstlane -> scalar base addrs
//  - each thread gathers its float2 slice of the 32 ctx rows into registers
//    (loaded ONCE, reused for the weighted sum)
//  - dist_sq[c]: per-thread partial -> wave shfl_xor tree -> cross-wave LDS
//  - weights via __expf (fp32, underflows to 0 exactly like the jnp reference)
__global__ __launch_bounds__(NTHREAD, 4) void kembed_kernel(
    const int* __restrict__ context,   // [B, C]
    const int* __restrict__ center,    // [B]
    const float* __restrict__ W,       // [V, D]
    float* __restrict__ out)           // [B, D]
{
    const int b    = blockIdx.x;
    const int tid  = threadIdx.x;
    const int lane = tid & 63;
    const int wid  = tid >> 6;

    __shared__ int   sidx[CTX];
    __shared__ float spart[CTX * 4];   // per-wave partial dist
    __shared__ float sdist[CTX];

    if (tid < CTX) sidx[tid] = context[b * CTX + tid];
    __syncthreads();

    const float2* __restrict__ Wv = (const float2*)W;

    const int cenIdx = __builtin_amdgcn_readfirstlane(center[b]);
    const float2 cen = Wv[(size_t)cenIdx * (DIM / 2) + tid];

    // Gather all 32 context rows (this thread's float2 slice) into registers.
    float2 x[CTX];
#pragma unroll
    for (int c = 0; c < CTX; ++c) {
        const int idx = __builtin_amdgcn_readfirstlane(sidx[c]);
        x[c] = Wv[(size_t)idx * (DIM / 2) + tid];
    }

    // dist_sq per context: wave-level butterfly reduce, then cross-wave LDS.
#pragma unroll
    for (int c = 0; c < CTX; ++c) {
        const float dx = x[c].x - cen.x;
        const float dy = x[c].y - cen.y;
        float v = dx * dx + dy * dy;
#pragma unroll
        for (int off = 32; off >= 1; off >>= 1)
            v += __shfl_xor(v, off, 64);
        if (lane == 0) spart[c * 4 + wid] = v;
    }
    __syncthreads();
    if (tid < CTX) {
        sdist[tid] = (spart[tid * 4 + 0] + spart[tid * 4 + 1]) +
                     (spart[tid * 4 + 2] + spart[tid * 4 + 3]);
    }
    __syncthreads();

    // Weight sum (recompute exp in second pass to save 32 VGPRs).
    float wsum = 0.f;
#pragma unroll
    for (int c = 0; c < CTX; ++c)
        wsum += __expf(-0.5f * sdist[c]);
    const float inv = 1.0f / (wsum + 1e-8f);

    float2 acc = make_float2(0.f, 0.f);
#pragma unroll
    for (int c = 0; c < CTX; ++c) {
        const float wc = __expf(-0.5f * sdist[c]) * inv;
        acc.x += wc * x[c].x;
        acc.y += wc * x[c].y;
    }

    ((float2*)out)[(size_t)b * (DIM / 2) + tid] = acc;
}

extern "C" void kernel_launch(void* const* d_in, const int* in_sizes, int n_in,
                              void* d_out, int out_size, void* d_ws, size_t ws_size,
                              hipStream_t stream) {
    const int*   context = (const int*)d_in[0];   // [B, C] int32
    const int*   center  = (const int*)d_in[1];   // [B] int32
    const float* W       = (const float*)d_in[2]; // [V, D] fp32
    float*       out     = (float*)d_out;         // [B, D] fp32

    kembed_kernel<<<BATCH, NTHREAD, 0, stream>>>(context, center, W, out);
}